// Round 11
// baseline (70.990 us; speedup 1.0000x reference)
//
#include <hip/hip_runtime.h>

#define BATCH 32
#define SEQ   2048
#define KD    512
#define QD    1024
#define HD    128

#define NT 16          // K-steps of 32
#define ROWS 16        // rows per block
#define NCHUNK 128     // 16-row chunks per batch

typedef float    f32x4 __attribute__((ext_vector_type(4)));
typedef _Float16 f16x8 __attribute__((ext_vector_type(8)));
typedef unsigned int u32;

__device__ __forceinline__ u32 pack2h(float a, float b) {
    _Float16 ha = (_Float16)a, hb = (_Float16)b;   // v_cvt_f16_f32 (RNE)
    unsigned short ua = __builtin_bit_cast(unsigned short, ha);
    unsigned short ub = __builtin_bit_cast(unsigned short, hb);
    return (u32)ua | ((u32)ub << 16);
}

// two f32x4 (8 consecutive k-floats) -> f16x8
__device__ __forceinline__ f16x8 cvtA4(const f32x4& r0, const f32x4& r1) {
    uint4 u = make_uint4(pack2h(r0[0], r0[1]), pack2h(r0[2], r0[3]),
                         pack2h(r1[0], r1[1]), pack2h(r1[2], r1[3]));
    return __builtin_bit_cast(f16x8, u);
}

__device__ __forceinline__ void gload_lds16(const void* g, void* l) {
    __builtin_amdgcn_global_load_lds(
        (const __attribute__((address_space(1))) unsigned int*)g,
        (__attribute__((address_space(3))) unsigned int*)l, 16, 0, 0);
}

// ---------------------------------------------------------------- prep
// blocks [0,512): q_proj
// blocks [512,528): W2 -> per-fragment f16 images (R4/R9-verified layout):
//   w2img[(t*512 + hj*64 + lane)*16] = f16 W2[hj*16+(lane&15)][t*32+(lane>>4)*8 ..+8)
__global__ __launch_bounds__(256) void prep_kernel(
        const float* __restrict__ query, const float* __restrict__ W1,
        const float* __restrict__ W2, float* __restrict__ qp,
        char* __restrict__ w2img) {
    int blk = blockIdx.x;
    int tid = threadIdx.x;
    if (blk < 512) {
        int b = blk >> 4, hg = blk & 15;
        int wave = tid >> 6, lane = tid & 63;
        int h = hg * 8 + wave * 2 + (lane >> 5);
        int l32 = lane & 31;
        const float* q = query + (size_t)b * QD;
        const float* w = W1 + (size_t)h * QD;
        float acc = 0.f;
        #pragma unroll
        for (int i = 0; i < 8; ++i) {
            float4 qv = *(const float4*)(q + i * 128 + l32 * 4);
            float4 wv = *(const float4*)(w + i * 128 + l32 * 4);
            acc += qv.x * wv.x + qv.y * wv.y + qv.z * wv.z + qv.w * wv.w;
        }
        #pragma unroll
        for (int off = 16; off >= 1; off >>= 1) acc += __shfl_xor(acc, off);
        if (l32 == 0) qp[b * HD + h] = acc;
    } else {
        int t = blk - 512;
        #pragma unroll
        for (int rep = 0; rep < 2; ++rep) {
            int f  = tid + rep * 256;        // frag 0..511
            int hj = f >> 6;
            int ln = f & 63;
            int r  = hj * 16 + (ln & 15);
            int c  = t * 32 + (ln >> 4) * 8;
            const float* src = W2 + (size_t)r * KD + c;
            float4 v0 = *(const float4*)(src);
            float4 v1 = *(const float4*)(src + 4);
            uint4 u = make_uint4(pack2h(v0.x, v0.y), pack2h(v0.z, v0.w),
                                 pack2h(v1.x, v1.y), pack2h(v1.z, v1.w));
            *(uint4*)(w2img + ((size_t)t * 512 + f) * 16) = u;
        }
    }
}

// ---------------------------------------------------------------- score + ctx
// 16 rows/block, 4096 blocks, 4 blocks/CU (16 waves/CU).
// Phase 1: keys tile fp32 -> LDS via 8 fire-and-forget global_load_lds per
//          wave (no VGPR dest, nothing to serialize); source granule-XOR
//          pre-swizzled (slot g holds global granule g^(row&7)) so all later
//          strided reads are conflict-light. ONE barrier.
// Phase 2: K-loop, barrier-free, HBM-free: A = 2 swizzled ds_read_b128 + cvt,
//          B = per-frag w2img direct from L2, 2 MFMA/iter (wave owns hj pair).
// Phase 3: cross-wave score reduce + tanh/V + softmax partials.
// Phase 4: ctx partial GEMV from the fp32 LDS tile (no global re-read).
__global__ __launch_bounds__(256, 4) void score_ctx_kernel(
        const float* __restrict__ keys, const char* __restrict__ w2img,
        const float* __restrict__ qp, const float* __restrict__ V,
        float* __restrict__ score_out, float* __restrict__ part_m,
        float* __restrict__ part_l, float* __restrict__ part_c) {
    __shared__ __align__(16) char kf[ROWS * 2048];   // 32 KB fp32, swizzled
    __shared__ float wpart[4][ROWS];
    __shared__ float pb[ROWS];

    const int blk  = blockIdx.x;          // 0..4095
    const int m0   = blk * ROWS;
    const int b    = blk >> 7;            // 128 chunks per batch
    const int tid  = threadIdx.x;
    const int wave = tid >> 6;
    const int lane = tid & 63;
    const int l15  = lane & 15;
    const int l4   = lane >> 4;

    // ---- phase 1: fire-and-forget stream (8 gload_lds per wave)
    {
        const char* kb = (const char*)(keys + (size_t)m0 * KD);
        #pragma unroll
        for (int j = 0; j < 8; ++j) {
            int row  = wave * 4 + (j >> 1);          // 0..15
            int slot = (j & 1) * 64 + lane;          // 16B granule slot 0..127
            int gg   = slot ^ (row & 7);             // inverse swizzle (involution)
            gload_lds16(kb + (size_t)row * 2048 + gg * 16,
                        kf + wave * 8192 + j * 1024 + lane * 16);
        }
    }
    __syncthreads();   // drains vmcnt once; tile complete

    // ---- phase 2: K-loop (no barriers, no HBM)
    const int hj0 = wave * 2;
    const char* bsrc = w2img + ((size_t)hj0 * 64 + lane) * 16;  // +t*8192, +1024
    const char* arow = kf + l15 * 2048;
    const int r7 = l15 & 7;

    f32x4 acc0 = (f32x4)0.f, acc1 = (f32x4)0.f;
    #pragma unroll
    for (int t = 0; t < NT; ++t) {
        int g = l4 * 2 + t * 8;                      // logical 16B granule
        f32x4 a0 = *(const f32x4*)(arow + ((g ^ r7) * 16));
        f32x4 a1 = *(const f32x4*)(arow + (((g + 1) ^ r7) * 16));
        f16x8 af = cvtA4(a0, a1);
        f16x8 b0 = *(const f16x8*)(bsrc + (size_t)t * 8192);
        f16x8 b1 = *(const f16x8*)(bsrc + (size_t)t * 8192 + 1024);
        acc0 = __builtin_amdgcn_mfma_f32_16x16x32_f16(af, b0, acc0, 0, 0, 0);
        acc1 = __builtin_amdgcn_mfma_f32_16x16x32_f16(af, b1, acc1, 0, 0, 0);
    }

    // ---- phase 3: scores. C/D: h = hj*16 + l15, key row = l4*4 + j
    float qv0 = qp[b * HD + hj0 * 16 + l15];
    float qv1 = qp[b * HD + hj0 * 16 + 16 + l15];
    float vv0 = V[hj0 * 16 + l15];
    float vv1 = V[hj0 * 16 + 16 + l15];
    #pragma unroll
    for (int j = 0; j < 4; ++j) {
        float x0 = qv0 + acc0[j];
        float x1 = qv1 + acc1[j];
        float e0 = __expf(2.f * x0);
        float e1 = __expf(2.f * x1);
        float p = (1.f - 2.f * __builtin_amdgcn_rcpf(1.f + e0)) * vv0
                + (1.f - 2.f * __builtin_amdgcn_rcpf(1.f + e1)) * vv1;
        #pragma unroll
        for (int off = 1; off < 16; off <<= 1) p += __shfl_xor(p, off);
        if (l15 == 0) wpart[wave][l4 * 4 + j] = p;
    }
    __syncthreads();

    int r = lane & 15;
    float prow = wpart[0][r] + wpart[1][r] + wpart[2][r] + wpart[3][r];
    float mx = prow;
    #pragma unroll
    for (int off = 1; off < 16; off <<= 1) mx = fmaxf(mx, __shfl_xor(mx, off));
    float e = __expf(prow - mx);
    float ls = e;
    #pragma unroll
    for (int off = 1; off < 16; off <<= 1) ls += __shfl_xor(ls, off);
    if (wave == 0 && lane < 16) {
        score_out[m0 + r] = prow;
        pb[r] = e;
    }
    if (tid == 0) {
        part_m[blk] = mx;
        part_l[blk] = ls;
    }
    __syncthreads();

    // ---- phase 4: ctx partial GEMV from fp32 LDS tile
    int col  = tid * 2;                    // 0..510
    int gsl  = tid >> 1;                   // granule slot base
    int off8 = (tid & 1) * 8;
    float c0 = 0.f, c1 = 0.f;
    #pragma unroll 4
    for (int s = 0; s < ROWS; ++s) {
        const char* p = kf + s * 2048 + ((gsl ^ (s & 7)) * 16) + off8;
        float2 kv = *(const float2*)p;
        c0 = fmaf(pb[s], kv.x, c0);
        c1 = fmaf(pb[s], kv.y, c1);
    }
    *(float2*)(part_c + (size_t)blk * KD + col) = make_float2(c0, c1);
}

// ---------------------------------------------------------------- finalize
__global__ __launch_bounds__(256) void finalize_kernel(
        const float* __restrict__ part_m, const float* __restrict__ part_l,
        const float* __restrict__ part_c, float* __restrict__ ctx,
        float* __restrict__ wts) {
    __shared__ float eS[NCHUNK];
    int b = blockIdx.x;
    int tid = threadIdx.x;
    float M = -1e30f;
    #pragma unroll 8
    for (int i = 0; i < NCHUNK; ++i) M = fmaxf(M, part_m[b * NCHUNK + i]);
    if (tid < NCHUNK) eS[tid] = __expf(part_m[b * NCHUNK + tid] - M);
    __syncthreads();
    float L = 0.f;
    #pragma unroll 8
    for (int i = 0; i < NCHUNK; ++i) L += eS[i] * part_l[b * NCHUNK + i];
    float invL = 1.f / L;
    #pragma unroll
    for (int r = 0; r < 8; ++r) {
        int s = tid + r * 256;
        float scv = wts[b * SEQ + s];
        wts[b * SEQ + s] = __expf(scv - M) * invL;
    }
    int col = tid * 2;
    float c0 = 0.f, c1 = 0.f;
    #pragma unroll 8
    for (int i = 0; i < NCHUNK; ++i) {
        float w = eS[i];
        float2 pc = *(const float2*)(part_c + (size_t)(b * NCHUNK + i) * KD + col);
        c0 = fmaf(w, pc.x, c0);
        c1 = fmaf(w, pc.y, c1);
    }
    ctx[b * KD + col]     = c0 * invL;
    ctx[b * KD + col + 1] = c1 * invL;
}

// ---------------------------------------------------------------- launch
extern "C" void kernel_launch(void* const* d_in, const int* in_sizes, int n_in,
                              void* d_out, int out_size, void* d_ws, size_t ws_size,
                              hipStream_t stream) {
    const float* query = (const float*)d_in[0];
    const float* keys  = (const float*)d_in[1];
    const float* W1    = (const float*)d_in[2];
    const float* W2    = (const float*)d_in[3];
    const float* V     = (const float*)d_in[4];

    float* ctx = (float*)d_out;
    float* wts = (float*)d_out + BATCH * KD;

    char* wsb     = (char*)d_ws;
    float* qp     = (float*)wsb;                       // 16 KB
    char*  w2img  = wsb + 16 * 1024;                   // 128 KB
    float* part_m = (float*)(wsb + 144 * 1024);        // 16 KB
    float* part_l = (float*)(wsb + 160 * 1024);        // 16 KB
    float* part_c = (float*)(wsb + 176 * 1024);        // 8 MB

    prep_kernel<<<528, 256, 0, stream>>>(query, W1, W2, qp, w2img);
    score_ctx_kernel<<<BATCH * NCHUNK, 256, 0, stream>>>(
        keys, w2img, qp, V, wts, part_m, part_l, part_c);
    finalize_kernel<<<BATCH, 256, 0, stream>>>(part_m, part_l, part_c, ctx, wts);
}